// Round 6
// baseline (879.357 us; speedup 1.0000x reference)
//
#include <hip/hip_runtime.h>
#include <math.h>

#define TPB 256
#define BSH 7                  // 128 nodes per bucket
#define NPB (1 << BSH)         // nodes per bucket
#define BMAX 1024              // max buckets (N <= 131072)
#define EPB 4096               // edges per block in hist/bucket passes

// ---------------- CSR build (bucketed, no global random atomics) ----------------

// pass A: coarse histogram of dst by bucket
__global__ __launch_bounds__(TPB) void k_hist(const int* __restrict__ dst,
                                              int* __restrict__ bucketCnt,
                                              int nE, int nbuck) {
  __shared__ int h[BMAX];
  for (int i = threadIdx.x; i < BMAX; i += TPB) h[i] = 0;
  __syncthreads();
  int base = blockIdx.x * EPB;
  for (int i = threadIdx.x; i < EPB; i += TPB) {
    int e = base + i;
    if (e < nE) atomicAdd(&h[dst[e] >> BSH], 1);
  }
  __syncthreads();
  for (int i = threadIdx.x; i < nbuck; i += TPB)
    if (h[i]) atomicAdd(&bucketCnt[i], h[i]);
}

// pass B: scan bucket counts -> bOff[nbuck+1], init gCur, set rowPtr[n]=nE
__global__ __launch_bounds__(BMAX) void k_bscan(const int* __restrict__ bucketCnt,
                                                int* __restrict__ bOff,
                                                int* __restrict__ gCur,
                                                int* __restrict__ rowPtr,
                                                int nbuck, int n, int nE) {
  __shared__ int sd[BMAX];
  int t = threadIdx.x;
  int v = (t < nbuck) ? bucketCnt[t] : 0;
  sd[t] = v;
  __syncthreads();
  for (int off = 1; off < BMAX; off <<= 1) {
    int add = (t >= off) ? sd[t - off] : 0;
    __syncthreads();
    sd[t] += add;
    __syncthreads();
  }
  if (t < nbuck) {
    bOff[t + 1] = sd[t];
    gCur[t] = sd[t] - v;     // exclusive prefix
  }
  if (t == 0) { bOff[0] = 0; rowPtr[n] = nE; }
}

// pass C: scatter packed (src | dlocal<<20) into bucket-sorted pairBuf
__global__ __launch_bounds__(TPB) void k_bucket(const int* __restrict__ src,
                                                const int* __restrict__ dst,
                                                int* __restrict__ gCur,
                                                int* __restrict__ pairBuf,
                                                int nE, int nbuck) {
  __shared__ int   hist[BMAX];
  __shared__ int   baseL[BMAX];
  __shared__ int   sp[EPB];
  __shared__ short sbk[EPB];
  for (int i = threadIdx.x; i < BMAX; i += TPB) hist[i] = 0;
  __syncthreads();
  int cb = blockIdx.x * EPB;
  for (int i = threadIdx.x; i < EPB; i += TPB) {
    int e = cb + i;
    if (e < nE) {
      int s = src[e], d = dst[e];
      int b = d >> BSH;
      sp[i]  = s | ((d & (NPB - 1)) << 20);
      sbk[i] = (short)b;
      atomicAdd(&hist[b], 1);
    } else sbk[i] = -1;
  }
  __syncthreads();
  for (int i = threadIdx.x; i < nbuck; i += TPB)
    baseL[i] = hist[i] ? atomicAdd(&gCur[i], hist[i]) : 0;
  __syncthreads();
  for (int i = threadIdx.x; i < BMAX; i += TPB) hist[i] = 0;  // reuse as cursor
  __syncthreads();
  for (int i = threadIdx.x; i < EPB; i += TPB) {
    int b = sbk[i];
    if (b >= 0) {
      int r = atomicAdd(&hist[b], 1);
      pairBuf[baseL[b] + r] = sp[i];
    }
  }
}

// pass D: per-bucket CSR finalize (rowPtr, col, dinv) — all ranking in LDS
__global__ __launch_bounds__(TPB) void k_final(const int* __restrict__ pairBuf,
                                               const int* __restrict__ bOff,
                                               int* __restrict__ rowPtr,
                                               int* __restrict__ col,
                                               float* __restrict__ dinv,
                                               int n) {
  __shared__ int h[NPB];
  __shared__ int ex[NPB];
  int t = threadIdx.x;
  int b = blockIdx.x;
  int p0 = bOff[b], p1 = bOff[b + 1];
  if (t < NPB) h[t] = 0;
  __syncthreads();
  for (int i = p0 + t; i < p1; i += TPB)
    atomicAdd(&h[pairBuf[i] >> 20], 1);
  __syncthreads();
  int v = 0;
  if (t < NPB) { v = h[t]; ex[t] = v; }
  __syncthreads();
  for (int off = 1; off < NPB; off <<= 1) {
    int add = 0;
    if (t < NPB && t >= off) add = ex[t - off];
    __syncthreads();
    if (t < NPB) ex[t] += add;
    __syncthreads();
  }
  if (t < NPB) {
    int node = (b << BSH) + t;
    if (node < n) {
      int excl = ex[t] - v;
      rowPtr[node] = p0 + excl;
      dinv[node]   = rsqrtf((float)(v + 1));  // +1 self loop
      h[t] = excl;  // reuse as per-local-node cursor
    }
  }
  __syncthreads();
  for (int i = p0 + t; i < p1; i += TPB) {
    int p = pairBuf[i];
    int r = atomicAdd(&h[p >> 20], 1);
    col[p0 + r] = p & 0xFFFFF;
  }
}

// ---------------- per-layer kernels ----------------
// Feature layout for hidden buffers: SLICED — buf[s][node][c], s<8, c<8,
// i.e. offset = s*N8 + node*8 + c (N8 = N*8). Slice s is processed only by
// blocks with blockIdx%8==s in k_scat8, which lands each slice on one XCD
// (round-robin dispatch) so its 3.2 MB fits that XCD's 4 MB private L2.

// HWS = (act(H) @ W) * dinv[n]; H read dense (layer 0) or sliced; HWS written sliced.
__global__ __launch_bounds__(TPB, 4) void k_gemm(const float* __restrict__ H,
                                                 const float* __restrict__ W,
                                                 const float* __restrict__ dinv,
                                                 float* __restrict__ HWS,
                                                 int relu, int denseIn,
                                                 int rows, int N8) {
  __shared__ float Wl[64 * 64];     // [k][c]
  __shared__ float Hl[64][68];      // [r][k], padded
  const int tid = threadIdx.x;
  const int c0 = (tid & 15) * 4;    // 4 consecutive cols
  const int r0 = (tid >> 4) * 4;    // 4 consecutive rows
  const int row0 = blockIdx.x * 64;

  for (int i = tid; i < 64 * 16; i += TPB)
    ((float4*)Wl)[i] = ((const float4*)W)[i];

  if (denseIn) {
    for (int i = tid; i < 64 * 16; i += TPB) {
      int r = i >> 4, q = i & 15;
      int gr = row0 + r;
      float4 v = make_float4(0.f, 0.f, 0.f, 0.f);
      if (gr < rows) v = ((const float4*)(H + (size_t)gr * 64))[q];
      if (relu) {
        v.x = fmaxf(v.x, 0.f); v.y = fmaxf(v.y, 0.f);
        v.z = fmaxf(v.z, 0.f); v.w = fmaxf(v.w, 0.f);
      }
      *(float4*)&Hl[r][q * 4] = v;
    }
  } else {
    // sliced read: i -> slice s=i>>7, j=i&127, row r=j>>1, half=j&1
    for (int i = tid; i < 64 * 16; i += TPB) {
      int s = i >> 7, j = i & 127, r = j >> 1, half = j & 1;
      int gr = row0 + r;
      float4 v = make_float4(0.f, 0.f, 0.f, 0.f);
      if (gr < rows)
        v = *(const float4*)&H[(size_t)s * N8 + (size_t)gr * 8 + half * 4];
      if (relu) {
        v.x = fmaxf(v.x, 0.f); v.y = fmaxf(v.y, 0.f);
        v.z = fmaxf(v.z, 0.f); v.w = fmaxf(v.w, 0.f);
      }
      *(float4*)&Hl[r][s * 8 + half * 4] = v;
    }
  }
  __syncthreads();

  float acc[4][4] = {{0.f,0.f,0.f,0.f},{0.f,0.f,0.f,0.f},
                     {0.f,0.f,0.f,0.f},{0.f,0.f,0.f,0.f}};
#pragma unroll 4
  for (int k = 0; k < 64; ++k) {
    float4 w = *(const float4*)&Wl[k * 64 + c0];
    float h0 = Hl[r0 + 0][k];
    float h1 = Hl[r0 + 1][k];
    float h2 = Hl[r0 + 2][k];
    float h3 = Hl[r0 + 3][k];
    acc[0][0] = fmaf(h0, w.x, acc[0][0]); acc[0][1] = fmaf(h0, w.y, acc[0][1]);
    acc[0][2] = fmaf(h0, w.z, acc[0][2]); acc[0][3] = fmaf(h0, w.w, acc[0][3]);
    acc[1][0] = fmaf(h1, w.x, acc[1][0]); acc[1][1] = fmaf(h1, w.y, acc[1][1]);
    acc[1][2] = fmaf(h1, w.z, acc[1][2]); acc[1][3] = fmaf(h1, w.w, acc[1][3]);
    acc[2][0] = fmaf(h2, w.x, acc[2][0]); acc[2][1] = fmaf(h2, w.y, acc[2][1]);
    acc[2][2] = fmaf(h2, w.z, acc[2][2]); acc[2][3] = fmaf(h2, w.w, acc[2][3]);
    acc[3][0] = fmaf(h3, w.x, acc[3][0]); acc[3][1] = fmaf(h3, w.y, acc[3][1]);
    acc[3][2] = fmaf(h3, w.z, acc[3][2]); acc[3][3] = fmaf(h3, w.w, acc[3][3]);
  }

  const int sOut = (tid & 15) >> 1;        // c0 >> 3
  const int cc   = (tid & 1) * 4;          // c0 & 7
#pragma unroll
  for (int i = 0; i < 4; ++i) {
    int gr = row0 + r0 + i;
    if (gr < rows) {
      float s = dinv[gr];
      float4 o = make_float4(acc[i][0] * s, acc[i][1] * s,
                             acc[i][2] * s, acc[i][3] * s);
      *(float4*)&HWS[(size_t)sOut * N8 + (size_t)gr * 8 + cc] = o;
    }
  }
}

// Sliced aggregate: OUT[s][n][c] = dinv[n]*(HWS[s][n][c] + sum_e HWS[s][col[e]][c]) + bias[s*8+c]
// slice = blockIdx%8 -> one slice per XCD (3.2MB, L2-resident).
// thread t: node = grp*32 + (t>>3), channel c = t&7.
__global__ __launch_bounds__(TPB) void k_scat8(const float* __restrict__ HWS,
                                               const int* __restrict__ rowPtr,
                                               const int* __restrict__ col,
                                               const float* __restrict__ dinv,
                                               const float* __restrict__ bias,
                                               float* __restrict__ OUT,
                                               int n, int N8) {
  const int slice = blockIdx.x & 7;
  const int grp   = blockIdx.x >> 3;
  const int t     = threadIdx.x;
  const int node  = grp * 32 + (t >> 3);
  const int c     = t & 7;
  if (node >= n) return;

  const float* __restrict__ tab = HWS + (size_t)slice * N8;
  float acc = tab[(size_t)node * 8 + c];   // self loop (pre-scaled by dinv in gemm)

  const int e1 = rowPtr[node + 1];
  int e = rowPtr[node];
  for (; e + 8 <= e1; e += 8) {
    int i0 = col[e],     i1 = col[e + 1], i2 = col[e + 2], i3 = col[e + 3];
    int i4 = col[e + 4], i5 = col[e + 5], i6 = col[e + 6], i7 = col[e + 7];
    float v0 = tab[(size_t)i0 * 8 + c];
    float v1 = tab[(size_t)i1 * 8 + c];
    float v2 = tab[(size_t)i2 * 8 + c];
    float v3 = tab[(size_t)i3 * 8 + c];
    float v4 = tab[(size_t)i4 * 8 + c];
    float v5 = tab[(size_t)i5 * 8 + c];
    float v6 = tab[(size_t)i6 * 8 + c];
    float v7 = tab[(size_t)i7 * 8 + c];
    acc += ((v0 + v1) + (v2 + v3)) + ((v4 + v5) + (v6 + v7));
  }
  for (; e + 4 <= e1; e += 4) {
    int i0 = col[e], i1 = col[e + 1], i2 = col[e + 2], i3 = col[e + 3];
    float v0 = tab[(size_t)i0 * 8 + c];
    float v1 = tab[(size_t)i1 * 8 + c];
    float v2 = tab[(size_t)i2 * 8 + c];
    float v3 = tab[(size_t)i3 * 8 + c];
    acc += (v0 + v1) + (v2 + v3);
  }
  for (; e < e1; ++e) acc += tab[(size_t)col[e] * 8 + c];

  OUT[(size_t)slice * N8 + (size_t)node * 8 + c] =
      dinv[node] * acc + bias[slice * 8 + c];
}

// hws1[n] = (relu(H[n]) . Wo) * dinv[n]  — H sliced
__global__ __launch_bounds__(TPB) void k_fdot(const float* __restrict__ H,
                                              const float* __restrict__ Wo,
                                              const float* __restrict__ dinv,
                                              float* __restrict__ hws1,
                                              int n, int N8) {
  int i = blockIdx.x * TPB + threadIdx.x;
  if (i >= n) return;
  float acc = 0.f;
#pragma unroll
  for (int s = 0; s < 8; ++s) {
    float4 a = *(const float4*)&H[(size_t)s * N8 + (size_t)i * 8];
    float4 b = *(const float4*)&H[(size_t)s * N8 + (size_t)i * 8 + 4];
    acc += fmaxf(a.x, 0.f) * Wo[s * 8 + 0];
    acc += fmaxf(a.y, 0.f) * Wo[s * 8 + 1];
    acc += fmaxf(a.z, 0.f) * Wo[s * 8 + 2];
    acc += fmaxf(a.w, 0.f) * Wo[s * 8 + 3];
    acc += fmaxf(b.x, 0.f) * Wo[s * 8 + 4];
    acc += fmaxf(b.y, 0.f) * Wo[s * 8 + 5];
    acc += fmaxf(b.z, 0.f) * Wo[s * 8 + 6];
    acc += fmaxf(b.w, 0.f) * Wo[s * 8 + 7];
  }
  hws1[i] = acc * dinv[i];
}

__global__ __launch_bounds__(TPB) void k_fscat(const float* __restrict__ hws1,
                                               const int* __restrict__ rowPtr,
                                               const int* __restrict__ col,
                                               const float* __restrict__ dinv,
                                               const float* __restrict__ bo,
                                               float* __restrict__ out, int n) {
  int i = blockIdx.x * TPB + threadIdx.x;
  if (i >= n) return;
  float a0 = hws1[i], a1 = 0.f, a2 = 0.f, a3 = 0.f;
  int e0 = rowPtr[i], e1 = rowPtr[i + 1];
  int e = e0;
  for (; e + 4 <= e1; e += 4) {
    a0 += hws1[col[e]];
    a1 += hws1[col[e + 1]];
    a2 += hws1[col[e + 2]];
    a3 += hws1[col[e + 3]];
  }
  for (; e < e1; ++e) a0 += hws1[col[e]];
  out[i] = dinv[i] * ((a0 + a1) + (a2 + a3)) + bo[0];
}

// ---------------- launch ----------------

extern "C" void kernel_launch(void* const* d_in, const int* in_sizes, int n_in,
                              void* d_out, int out_size, void* d_ws, size_t ws_size,
                              hipStream_t stream) {
  const float* x   = (const float*)d_in[0];
  const int*   ei  = (const int*)d_in[1];
  const float* W_i = (const float*)d_in[2];
  const float* b_i = (const float*)d_in[3];
  const float* W_h = (const float*)d_in[4];
  const float* b_h = (const float*)d_in[5];
  const float* W_o = (const float*)d_in[6];
  const float* b_o = (const float*)d_in[7];

  const int N = in_sizes[0] / 64;   // 100000
  const int E = in_sizes[1] / 2;    // 2000000
  const int N8 = N * 8;
  const int* srcArr = ei;           // edge_index[0]
  const int* dstArr = ei + E;       // edge_index[1]
  const int nbuck = (N + NPB - 1) >> BSH;   // 782

  char* w = (char*)d_ws;
  auto take = [&](size_t bytes) -> char* {
    char* p = w;
    w += (bytes + 255) & ~(size_t)255;
    return p;
  };
  int*   rowPtr    = (int*)take((size_t)(N + 1) * 4);
  int*   col       = (int*)take((size_t)E * 4);
  float* dinv      = (float*)take((size_t)N * 4);
  int*   bucketCnt = (int*)take((size_t)BMAX * 4);
  int*   bOff      = (int*)take((size_t)(BMAX + 1) * 4);
  int*   gCur      = (int*)take((size_t)BMAX * 4);
  float* bufH      = (float*)take((size_t)N * 64 * 4);
  float* bufS      = (float*)take((size_t)N * 64 * 4);
  float* hws1      = (float*)take((size_t)N * 4);
  int*   pairBuf   = (int*)bufS;   // alias: bufS unused during CSR build
  (void)ws_size; (void)n_in; (void)out_size;

  const int nbN    = (N + TPB - 1) / TPB;
  const int nbEd   = (E + EPB - 1) / EPB;
  const int nbGemm = (N + 63) / 64;
  const int nbScat = 8 * ((N + 31) / 32);   // slice-major: blockIdx%8 = slice

  // CSR build + dinv
  hipMemsetAsync(bucketCnt, 0, (size_t)BMAX * 4, stream);
  k_hist  <<<nbEd, TPB, 0, stream>>>(dstArr, bucketCnt, E, nbuck);
  k_bscan <<<1, BMAX, 0, stream>>>(bucketCnt, bOff, gCur, rowPtr, nbuck, N, E);
  k_bucket<<<nbEd, TPB, 0, stream>>>(srcArr, dstArr, gCur, pairBuf, E, nbuck);
  k_final <<<nbuck, TPB, 0, stream>>>(pairBuf, bOff, rowPtr, col, dinv, N);

  // layer 0: x (dense) -> bufS (sliced) -> bufH (sliced)
  k_gemm <<<nbGemm, TPB, 0, stream>>>(x, W_i, dinv, bufS, 0, 1, N, N8);
  k_scat8<<<nbScat, TPB, 0, stream>>>(bufS, rowPtr, col, dinv, b_i, bufH, N, N8);

  // 6 hidden layers (all sliced)
  for (int l = 0; l < 6; ++l) {
    k_gemm <<<nbGemm, TPB, 0, stream>>>(bufH, W_h + (size_t)l * 64 * 64, dinv, bufS, 1, 0, N, N8);
    k_scat8<<<nbScat, TPB, 0, stream>>>(bufS, rowPtr, col, dinv, b_h + (size_t)l * 64, bufH, N, N8);
  }

  // output layer: 64 -> 1
  k_fdot <<<nbN, TPB, 0, stream>>>(bufH, W_o, dinv, hws1, N, N8);
  k_fscat<<<nbN, TPB, 0, stream>>>(hws1, rowPtr, col, dinv, b_o, (float*)d_out, N);
}

// Round 7
// 870.923 us; speedup vs baseline: 1.0097x; 1.0097x over previous
//
#include <hip/hip_runtime.h>
#include <math.h>

#define TPB 256
#define BSH 7                  // 128 nodes per bucket
#define NPB (1 << BSH)         // nodes per bucket
#define BMAX 1024              // max buckets (N <= 131072)
#define EPB 4096               // edges per block in hist/bucket passes

// ---------------- CSR build (bucketed, no global random atomics) ----------------

__global__ __launch_bounds__(TPB) void k_hist(const int* __restrict__ dst,
                                              int* __restrict__ bucketCnt,
                                              int nE, int nbuck) {
  __shared__ int h[BMAX];
  for (int i = threadIdx.x; i < BMAX; i += TPB) h[i] = 0;
  __syncthreads();
  int base = blockIdx.x * EPB;
  for (int i = threadIdx.x; i < EPB; i += TPB) {
    int e = base + i;
    if (e < nE) atomicAdd(&h[dst[e] >> BSH], 1);
  }
  __syncthreads();
  for (int i = threadIdx.x; i < nbuck; i += TPB)
    if (h[i]) atomicAdd(&bucketCnt[i], h[i]);
}

__global__ __launch_bounds__(BMAX) void k_bscan(const int* __restrict__ bucketCnt,
                                                int* __restrict__ bOff,
                                                int* __restrict__ gCur,
                                                int* __restrict__ rowPtr,
                                                int nbuck, int n, int nE) {
  __shared__ int sd[BMAX];
  int t = threadIdx.x;
  int v = (t < nbuck) ? bucketCnt[t] : 0;
  sd[t] = v;
  __syncthreads();
  for (int off = 1; off < BMAX; off <<= 1) {
    int add = (t >= off) ? sd[t - off] : 0;
    __syncthreads();
    sd[t] += add;
    __syncthreads();
  }
  if (t < nbuck) {
    bOff[t + 1] = sd[t];
    gCur[t] = sd[t] - v;     // exclusive prefix
  }
  if (t == 0) { bOff[0] = 0; rowPtr[n] = nE; }
}

__global__ __launch_bounds__(TPB) void k_bucket(const int* __restrict__ src,
                                                const int* __restrict__ dst,
                                                int* __restrict__ gCur,
                                                int* __restrict__ pairBuf,
                                                int nE, int nbuck) {
  __shared__ int   hist[BMAX];
  __shared__ int   baseL[BMAX];
  __shared__ int   sp[EPB];
  __shared__ short sbk[EPB];
  for (int i = threadIdx.x; i < BMAX; i += TPB) hist[i] = 0;
  __syncthreads();
  int cb = blockIdx.x * EPB;
  for (int i = threadIdx.x; i < EPB; i += TPB) {
    int e = cb + i;
    if (e < nE) {
      int s = src[e], d = dst[e];
      int b = d >> BSH;
      sp[i]  = s | ((d & (NPB - 1)) << 20);
      sbk[i] = (short)b;
      atomicAdd(&hist[b], 1);
    } else sbk[i] = -1;
  }
  __syncthreads();
  for (int i = threadIdx.x; i < nbuck; i += TPB)
    baseL[i] = hist[i] ? atomicAdd(&gCur[i], hist[i]) : 0;
  __syncthreads();
  for (int i = threadIdx.x; i < BMAX; i += TPB) hist[i] = 0;  // reuse as cursor
  __syncthreads();
  for (int i = threadIdx.x; i < EPB; i += TPB) {
    int b = sbk[i];
    if (b >= 0) {
      int r = atomicAdd(&hist[b], 1);
      pairBuf[baseL[b] + r] = sp[i];
    }
  }
}

__global__ __launch_bounds__(TPB) void k_final(const int* __restrict__ pairBuf,
                                               const int* __restrict__ bOff,
                                               int* __restrict__ rowPtr,
                                               int* __restrict__ col,
                                               float* __restrict__ dinv,
                                               int n) {
  __shared__ int h[NPB];
  __shared__ int ex[NPB];
  int t = threadIdx.x;
  int b = blockIdx.x;
  int p0 = bOff[b], p1 = bOff[b + 1];
  if (t < NPB) h[t] = 0;
  __syncthreads();
  for (int i = p0 + t; i < p1; i += TPB)
    atomicAdd(&h[pairBuf[i] >> 20], 1);
  __syncthreads();
  int v = 0;
  if (t < NPB) { v = h[t]; ex[t] = v; }
  __syncthreads();
  for (int off = 1; off < NPB; off <<= 1) {
    int add = 0;
    if (t < NPB && t >= off) add = ex[t - off];
    __syncthreads();
    if (t < NPB) ex[t] += add;
    __syncthreads();
  }
  if (t < NPB) {
    int node = (b << BSH) + t;
    if (node < n) {
      int excl = ex[t] - v;
      rowPtr[node] = p0 + excl;
      dinv[node]   = rsqrtf((float)(v + 1));  // +1 self loop
      h[t] = excl;  // reuse as per-local-node cursor
    }
  }
  __syncthreads();
  for (int i = p0 + t; i < p1; i += TPB) {
    int p = pairBuf[i];
    int r = atomicAdd(&h[p >> 20], 1);
    col[p0 + r] = p & 0xFFFFF;
  }
}

// ---------------- per-layer kernels ----------------
// Feature layout for hidden buffers: SLICED — buf[s][node][c], s<8, c<8,
// offset = s*N8 + node*8 + c (N8 = N*8). Slice s processed only by blocks
// with blockIdx%8==s -> round-robin dispatch pins each 3.2MB slice to one
// XCD's 4MB private L2 (verified round 6: FETCH 233->62MB).

__global__ __launch_bounds__(TPB, 4) void k_gemm(const float* __restrict__ H,
                                                 const float* __restrict__ W,
                                                 const float* __restrict__ dinv,
                                                 float* __restrict__ HWS,
                                                 int relu, int denseIn,
                                                 int rows, int N8) {
  __shared__ float Wl[64 * 64];     // [k][c]
  __shared__ float Hl[64][68];      // [r][k], padded
  const int tid = threadIdx.x;
  const int c0 = (tid & 15) * 4;    // 4 consecutive cols
  const int r0 = (tid >> 4) * 4;    // 4 consecutive rows
  const int row0 = blockIdx.x * 64;

  for (int i = tid; i < 64 * 16; i += TPB)
    ((float4*)Wl)[i] = ((const float4*)W)[i];

  if (denseIn) {
    for (int i = tid; i < 64 * 16; i += TPB) {
      int r = i >> 4, q = i & 15;
      int gr = row0 + r;
      float4 v = make_float4(0.f, 0.f, 0.f, 0.f);
      if (gr < rows) v = ((const float4*)(H + (size_t)gr * 64))[q];
      if (relu) {
        v.x = fmaxf(v.x, 0.f); v.y = fmaxf(v.y, 0.f);
        v.z = fmaxf(v.z, 0.f); v.w = fmaxf(v.w, 0.f);
      }
      *(float4*)&Hl[r][q * 4] = v;
    }
  } else {
    for (int i = tid; i < 64 * 16; i += TPB) {
      int s = i >> 7, j = i & 127, r = j >> 1, half = j & 1;
      int gr = row0 + r;
      float4 v = make_float4(0.f, 0.f, 0.f, 0.f);
      if (gr < rows)
        v = *(const float4*)&H[(size_t)s * N8 + (size_t)gr * 8 + half * 4];
      if (relu) {
        v.x = fmaxf(v.x, 0.f); v.y = fmaxf(v.y, 0.f);
        v.z = fmaxf(v.z, 0.f); v.w = fmaxf(v.w, 0.f);
      }
      *(float4*)&Hl[r][s * 8 + half * 4] = v;
    }
  }
  __syncthreads();

  float acc[4][4] = {{0.f,0.f,0.f,0.f},{0.f,0.f,0.f,0.f},
                     {0.f,0.f,0.f,0.f},{0.f,0.f,0.f,0.f}};
#pragma unroll 4
  for (int k = 0; k < 64; ++k) {
    float4 w = *(const float4*)&Wl[k * 64 + c0];
    float h0 = Hl[r0 + 0][k];
    float h1 = Hl[r0 + 1][k];
    float h2 = Hl[r0 + 2][k];
    float h3 = Hl[r0 + 3][k];
    acc[0][0] = fmaf(h0, w.x, acc[0][0]); acc[0][1] = fmaf(h0, w.y, acc[0][1]);
    acc[0][2] = fmaf(h0, w.z, acc[0][2]); acc[0][3] = fmaf(h0, w.w, acc[0][3]);
    acc[1][0] = fmaf(h1, w.x, acc[1][0]); acc[1][1] = fmaf(h1, w.y, acc[1][1]);
    acc[1][2] = fmaf(h1, w.z, acc[1][2]); acc[1][3] = fmaf(h1, w.w, acc[1][3]);
    acc[2][0] = fmaf(h2, w.x, acc[2][0]); acc[2][1] = fmaf(h2, w.y, acc[2][1]);
    acc[2][2] = fmaf(h2, w.z, acc[2][2]); acc[2][3] = fmaf(h2, w.w, acc[2][3]);
    acc[3][0] = fmaf(h3, w.x, acc[3][0]); acc[3][1] = fmaf(h3, w.y, acc[3][1]);
    acc[3][2] = fmaf(h3, w.z, acc[3][2]); acc[3][3] = fmaf(h3, w.w, acc[3][3]);
  }

  const int sOut = (tid & 15) >> 1;        // c0 >> 3
  const int cc   = (tid & 1) * 4;          // c0 & 7
#pragma unroll
  for (int i = 0; i < 4; ++i) {
    int gr = row0 + r0 + i;
    if (gr < rows) {
      float s = dinv[gr];
      float4 o = make_float4(acc[i][0] * s, acc[i][1] * s,
                             acc[i][2] * s, acc[i][3] * s);
      *(float4*)&HWS[(size_t)sOut * N8 + (size_t)gr * 8 + cc] = o;
    }
  }
}

// Sliced aggregate v2: 16-lane group per node; lane = (edge-slot es=gl>>1,
// half h=gl&1). Each lane gathers float4 (16B) of the 32B node-slice row ->
// one wave-inst moves 1KB over 32 edge-slices; 16-edge unroll keeps 2 col +
// 2 tab float4 loads in flight per lane (concurrency fix for round-6's
// latency bound). No shfl in the gather loop (2-lane col broadcast via HW),
// so predicated tails are safe. Cross-slot reduce: shfl_xor 2/4/8 within the
// group (group-uniform exec).
__global__ __launch_bounds__(TPB) void k_scat8(const float* __restrict__ HWS,
                                               const int* __restrict__ rowPtr,
                                               const int* __restrict__ col,
                                               const float* __restrict__ dinv,
                                               const float* __restrict__ bias,
                                               float* __restrict__ OUT,
                                               int n, int N8) {
  const int slice = blockIdx.x & 7;
  const int nb    = blockIdx.x >> 3;      // node-block index
  const int tid   = threadIdx.x;
  const int wv    = tid >> 6;             // wave 0..3
  const int lane  = tid & 63;
  const int g     = lane >> 4;            // group 0..3 (node within wave)
  const int gl    = lane & 15;
  const int es    = gl >> 1;              // edge slot 0..7
  const int h     = gl & 1;               // row half 0..1
  const int node  = nb * 16 + wv * 4 + g;
  if (node >= n) return;

  const float4* __restrict__ tab = (const float4*)(HWS + (size_t)slice * N8);

  // self loop (pre-scaled by dinv in gemm), counted once (slot 0 lanes)
  float4 acc = make_float4(0.f, 0.f, 0.f, 0.f);
  if (es == 0) acc = tab[(size_t)node * 2 + h];

  const int e0  = rowPtr[node];
  const int deg = rowPtr[node + 1] - e0;
  const int* __restrict__ cp = col + e0;

  int base = 0;
  for (; base + 16 <= deg; base += 16) {
    int i0 = cp[base + es];
    int i1 = cp[base + 8 + es];
    float4 v0 = tab[(size_t)i0 * 2 + h];
    float4 v1 = tab[(size_t)i1 * 2 + h];
    acc.x += v0.x + v1.x;
    acc.y += v0.y + v1.y;
    acc.z += v0.z + v1.z;
    acc.w += v0.w + v1.w;
  }
  // remainder (< 16): up to two predicated slots
  {
    int j0 = base + es;
    int j1 = base + 8 + es;
    if (j0 < deg) {
      int i0 = cp[j0];
      float4 v0 = tab[(size_t)i0 * 2 + h];
      acc.x += v0.x; acc.y += v0.y; acc.z += v0.z; acc.w += v0.w;
    }
    if (j1 < deg) {
      int i1 = cp[j1];
      float4 v1 = tab[(size_t)i1 * 2 + h];
      acc.x += v1.x; acc.y += v1.y; acc.z += v1.z; acc.w += v1.w;
    }
  }

  // reduce over the 8 edge slots: lanes {g*16 + 2k + h}, offsets 2,4,8
#pragma unroll
  for (int off = 2; off < 16; off <<= 1) {
    acc.x += __shfl_xor(acc.x, off, 64);
    acc.y += __shfl_xor(acc.y, off, 64);
    acc.z += __shfl_xor(acc.z, off, 64);
    acc.w += __shfl_xor(acc.w, off, 64);
  }

  if (es == 0) {
    float s = dinv[node];
    float4 b4 = *(const float4*)&bias[slice * 8 + h * 4];
    float4 o = make_float4(acc.x * s + b4.x, acc.y * s + b4.y,
                           acc.z * s + b4.z, acc.w * s + b4.w);
    *(float4*)&OUT[(size_t)slice * N8 + (size_t)node * 8 + h * 4] = o;
  }
}

// hws1[n] = (relu(H[n]) . Wo) * dinv[n]  — H sliced
__global__ __launch_bounds__(TPB) void k_fdot(const float* __restrict__ H,
                                              const float* __restrict__ Wo,
                                              const float* __restrict__ dinv,
                                              float* __restrict__ hws1,
                                              int n, int N8) {
  int i = blockIdx.x * TPB + threadIdx.x;
  if (i >= n) return;
  float acc = 0.f;
#pragma unroll
  for (int s = 0; s < 8; ++s) {
    float4 a = *(const float4*)&H[(size_t)s * N8 + (size_t)i * 8];
    float4 b = *(const float4*)&H[(size_t)s * N8 + (size_t)i * 8 + 4];
    acc += fmaxf(a.x, 0.f) * Wo[s * 8 + 0];
    acc += fmaxf(a.y, 0.f) * Wo[s * 8 + 1];
    acc += fmaxf(a.z, 0.f) * Wo[s * 8 + 2];
    acc += fmaxf(a.w, 0.f) * Wo[s * 8 + 3];
    acc += fmaxf(b.x, 0.f) * Wo[s * 8 + 4];
    acc += fmaxf(b.y, 0.f) * Wo[s * 8 + 5];
    acc += fmaxf(b.z, 0.f) * Wo[s * 8 + 6];
    acc += fmaxf(b.w, 0.f) * Wo[s * 8 + 7];
  }
  hws1[i] = acc * dinv[i];
}

__global__ __launch_bounds__(TPB) void k_fscat(const float* __restrict__ hws1,
                                               const int* __restrict__ rowPtr,
                                               const int* __restrict__ col,
                                               const float* __restrict__ dinv,
                                               const float* __restrict__ bo,
                                               float* __restrict__ out, int n) {
  int i = blockIdx.x * TPB + threadIdx.x;
  if (i >= n) return;
  float a0 = hws1[i], a1 = 0.f, a2 = 0.f, a3 = 0.f;
  int e0 = rowPtr[i], e1 = rowPtr[i + 1];
  int e = e0;
  for (; e + 4 <= e1; e += 4) {
    a0 += hws1[col[e]];
    a1 += hws1[col[e + 1]];
    a2 += hws1[col[e + 2]];
    a3 += hws1[col[e + 3]];
  }
  for (; e < e1; ++e) a0 += hws1[col[e]];
  out[i] = dinv[i] * ((a0 + a1) + (a2 + a3)) + bo[0];
}

// ---------------- launch ----------------

extern "C" void kernel_launch(void* const* d_in, const int* in_sizes, int n_in,
                              void* d_out, int out_size, void* d_ws, size_t ws_size,
                              hipStream_t stream) {
  const float* x   = (const float*)d_in[0];
  const int*   ei  = (const int*)d_in[1];
  const float* W_i = (const float*)d_in[2];
  const float* b_i = (const float*)d_in[3];
  const float* W_h = (const float*)d_in[4];
  const float* b_h = (const float*)d_in[5];
  const float* W_o = (const float*)d_in[6];
  const float* b_o = (const float*)d_in[7];

  const int N = in_sizes[0] / 64;   // 100000
  const int E = in_sizes[1] / 2;    // 2000000
  const int N8 = N * 8;
  const int* srcArr = ei;           // edge_index[0]
  const int* dstArr = ei + E;       // edge_index[1]
  const int nbuck = (N + NPB - 1) >> BSH;   // 782

  char* w = (char*)d_ws;
  auto take = [&](size_t bytes) -> char* {
    char* p = w;
    w += (bytes + 255) & ~(size_t)255;
    return p;
  };
  int*   rowPtr    = (int*)take((size_t)(N + 1) * 4);
  int*   col       = (int*)take((size_t)E * 4);
  float* dinv      = (float*)take((size_t)N * 4);
  int*   bucketCnt = (int*)take((size_t)BMAX * 4);
  int*   bOff      = (int*)take((size_t)(BMAX + 1) * 4);
  int*   gCur      = (int*)take((size_t)BMAX * 4);
  float* bufH      = (float*)take((size_t)N * 64 * 4);
  float* bufS      = (float*)take((size_t)N * 64 * 4);
  float* hws1      = (float*)take((size_t)N * 4);
  int*   pairBuf   = (int*)bufS;   // alias: bufS unused during CSR build
  (void)ws_size; (void)n_in; (void)out_size;

  const int nbN    = (N + TPB - 1) / TPB;
  const int nbEd   = (E + EPB - 1) / EPB;
  const int nbGemm = (N + 63) / 64;
  const int nbScat = 8 * ((N + 15) / 16);   // blockIdx%8 = slice, 16 nodes/block

  // CSR build + dinv
  hipMemsetAsync(bucketCnt, 0, (size_t)BMAX * 4, stream);
  k_hist  <<<nbEd, TPB, 0, stream>>>(dstArr, bucketCnt, E, nbuck);
  k_bscan <<<1, BMAX, 0, stream>>>(bucketCnt, bOff, gCur, rowPtr, nbuck, N, E);
  k_bucket<<<nbEd, TPB, 0, stream>>>(srcArr, dstArr, gCur, pairBuf, E, nbuck);
  k_final <<<nbuck, TPB, 0, stream>>>(pairBuf, bOff, rowPtr, col, dinv, N);

  // layer 0: x (dense) -> bufS (sliced) -> bufH (sliced)
  k_gemm <<<nbGemm, TPB, 0, stream>>>(x, W_i, dinv, bufS, 0, 1, N, N8);
  k_scat8<<<nbScat, TPB, 0, stream>>>(bufS, rowPtr, col, dinv, b_i, bufH, N, N8);

  // 6 hidden layers (all sliced)
  for (int l = 0; l < 6; ++l) {
    k_gemm <<<nbGemm, TPB, 0, stream>>>(bufH, W_h + (size_t)l * 64 * 64, dinv, bufS, 1, 0, N, N8);
    k_scat8<<<nbScat, TPB, 0, stream>>>(bufS, rowPtr, col, dinv, b_h + (size_t)l * 64, bufH, N, N8);
  }

  // output layer: 64 -> 1
  k_fdot <<<nbN, TPB, 0, stream>>>(bufH, W_o, dinv, hws1, N, N8);
  k_fscat<<<nbN, TPB, 0, stream>>>(hws1, rowPtr, col, dinv, b_o, (float*)d_out, N);
}